// Round 11
// baseline (129.561 us; speedup 1.0000x reference)
//
#include <hip/hip_runtime.h>
#include <hip/hip_bf16.h>
#include <hip/hip_fp16.h>

#define NB 8
#define NN 256
#define DD 64

// workspace layout (float offsets)
#define OFF_WCF   0        // 2048 f = 4096 f16 : Wc B-frags [ks][nt][lane][8]
#define OFF_W1F   2048     // 2048 f = 4096 f16 : 0.25*Ws1 B-frags, same order
#define OFF_CSF   4096     // 1536 f = 3072 f16 : h-coefs per lane [lane][coef][kslot16], stride 48
#define OFF_CC    5632     // 64   : cc[d] = 0.5*(bv2@Ws1)[d] + bs1[d]
#define OFF_MI    5704     // 2048 : per-row local max
#define OFF_RSI   7752     // 2048 : per-row rowsum (local frame)
#define OFF_SHR   9800     // 131072 : per-row Sh[64] (local frame)

typedef __attribute__((ext_vector_type(4))) float f32x4;
typedef _Float16 f16x8 __attribute__((ext_vector_type(8)));

static __device__ __forceinline__ f16x8 cvt2(float4 a, float4 c) {
    f16x8 r;
    r[0] = (_Float16)a.x; r[1] = (_Float16)a.y; r[2] = (_Float16)a.z; r[3] = (_Float16)a.w;
    r[4] = (_Float16)c.x; r[5] = (_Float16)c.y; r[6] = (_Float16)c.z; r[7] = (_Float16)c.w;
    return r;
}

// ---------------------------------------------------------------- setup ----
// 11328 items: WCF 4096 | W1F 4096 | CSF 3072 | CC 64
__global__ __launch_bounds__(256) void k_setup(
    const float* __restrict__ Wv1, const float* __restrict__ bv1,
    const float* __restrict__ Wv2, const float* __restrict__ bv2,
    const float* __restrict__ Ws1, const float* __restrict__ bs1,
    float* __restrict__ ws)
{
    int idx = blockIdx.x * 256 + threadIdx.x;
    if (idx < 4096) {
        // Wc = 0.5*Wv2@Ws1 -> f16 B-fragment order
        int e = idx;
        int j = e & 7, ln = (e >> 3) & 63, nt = (e >> 9) & 3, ks = e >> 11;
        int k = ks * 32 + (ln >> 4) * 8 + j;
        int d = nt * 16 + (ln & 15);
        float s = 0.f;
#pragma unroll 8
        for (int m = 0; m < 64; m++) s = fmaf(Wv2[k * 64 + m], Ws1[m * 64 + d], s);
        ((_Float16*)(ws + OFF_WCF))[e] = (_Float16)(0.5f * s);
    } else if (idx < 8192) {
        // 0.25*Ws1 -> f16 B-fragment order
        int e = idx - 4096;
        int j = e & 7, ln = (e >> 3) & 63, nt = (e >> 9) & 3, ks = e >> 11;
        int k = ks * 32 + (ln >> 4) * 8 + j;
        int d = nt * 16 + (ln & 15);
        ((_Float16*)(ws + OFF_W1F))[e] = (_Float16)(0.25f * Ws1[k * 64 + d]);
    } else if (idx < 11264) {
        // h-coefs: stride-48 per lane: [lane][coef(3)][kslot(16)]
        int e = idx - 8192;            // 0..3071
        int ln = e / 48;
        int rem = e - ln * 48;
        int coef = rem >> 4, kslot = rem & 15;
        int ks = kslot >> 3, j = kslot & 7;
        int k = ks * 32 + (ln >> 4) * 8 + j;
        float v = (coef == 0) ? Wv1[k] : (coef == 1) ? Wv1[64 + k] : bv1[k];
        ((_Float16*)(ws + OFF_CSF))[ln * 48 + coef * 16 + kslot] = (_Float16)v;
    } else if (idx < 11328) {
        int d = idx - 11264;
        float s = 0.f;
#pragma unroll 8
        for (int k = 0; k < 64; k++) s = fmaf(bv2[k], Ws1[k * 64 + d], s);
        ws[OFF_CC + d] = 0.5f * s + bs1[d];
    }
}

// ----------------------------------------------------------------- main ----
// PROBE ROUND: grid = 4096 = 2x redundant coverage of 8 batches * 256 rows.
// Duplicate blocks write identical values (idempotent) -> output unchanged,
// but the dispatch runs 2x the work so it rises above the harness fills in
// the profile and we finally get its counters.
__global__ __launch_bounds__(256, 4) void k_main(
    const float* __restrict__ pos, const float* __restrict__ values,
    const float* __restrict__ Wv1, const float* __restrict__ bv1,
    const float* __restrict__ Ws2, float* __restrict__ ws)
{
    __shared__ float2   ldsDB[256];    // (dot,biv) per j
    __shared__ float    ldsS[256];     // scores, then weights
    __shared__ float    ldsCC[64];
    __shared__ float    ldsWs2[64];
    __shared__ float    ldsPos[3];
    __shared__ float    ldsRedM[4];
    __shared__ float    ldsRedS[4];
    __shared__ float    ldsP[4][64];
    __shared__ _Float16 ldsW1[4096];   // 0.25*Ws1 B-frags

    int b = (blockIdx.x >> 8) & 7;     // duplicate coverage: blocks 2048..4095 redo b 0..7
    int i = blockIdx.x & 255;
    int t = threadIdx.x;
    int lane = t & 63, wv = t >> 6;
    int q = lane >> 4, col = lane & 15;

    const float* vB = values + b * (NN * DD);

    // ---- early prefetch: first j-tile's v rows (jt = wv*4 -> j = wv*64+col)
    float4 nf0, nf1, nf2, nf3;
    {
        const float* p = vB + (wv * 64 + col) * 64 + q * 8;
        nf0 = *(const float4*)p;        nf1 = *(const float4*)(p + 4);
        nf2 = *(const float4*)(p + 32); nf3 = *(const float4*)(p + 36);
    }
    // v_i rows for u_i (col==0 lanes only; others zero)
    float4 vi0 = {0,0,0,0}, vi1 = {0,0,0,0}, vi2 = {0,0,0,0}, vi3 = {0,0,0,0};
    if (col == 0) {
        const float* p = vB + i * 64 + q * 8;
        vi0 = *(const float4*)p;        vi1 = *(const float4*)(p + 4);
        vi2 = *(const float4*)(p + 32); vi3 = *(const float4*)(p + 36);
    }

    // ---- stage constants ----
    {
        const float4* src = (const float4*)(ws + OFF_W1F);
        float4* dst = (float4*)ldsW1;
        dst[t] = src[t];
        dst[256 + t] = src[256 + t];
    }
    if (t < 3)  ldsPos[t] = pos[(b * 256 + i) * 3 + t];
    if (t >= 64 && t < 128) ldsCC[t - 64] = ws[OFF_CC + t - 64];
    if (t >= 128 && t < 192) ldsWs2[t - 128] = Ws2[t - 128];

    // per-lane h-coefs (f16 packed)
    f16x8 cfA[2], cfB[2], cfC[2];
    {
        const f16x8* cs = (const f16x8*)((const _Float16*)(ws + OFF_CSF) + lane * 48);
        cfA[0] = cs[0]; cfA[1] = cs[1];
        cfB[0] = cs[2]; cfB[1] = cs[3];
        cfC[0] = cs[4]; cfC[1] = cs[5];
    }
    // Wc B-frags in registers
    f16x8 wcf[2][4];
    {
        const f16x8* p = (const f16x8*)(ws + OFF_WCF);
#pragma unroll
        for (int ks = 0; ks < 2; ks++)
#pragma unroll
            for (int nt = 0; nt < 4; nt++)
                wcf[ks][nt] = p[(ks * 4 + nt) * 64 + lane];
    }
    __syncthreads();

    {   // dot/biv vs all j (thread t = j); consumed wave-locally
        float px = pos[(b * 256 + t) * 3 + 0];
        float py = pos[(b * 256 + t) * 3 + 1];
        float pz = pos[(b * 256 + t) * 3 + 2];
        float ax = ldsPos[0], ay = ldsPos[1], az = ldsPos[2];
        float dot = ax * px + ay * py + az * pz;
        float cx = ay * pz - az * py;
        float cy = az * px - ax * pz;
        float cz = ax * py - ay * px;
        float biv = sqrtf(cx * cx + cy * cy + cz * cz + 1e-20f);
        ldsDB[t] = make_float2(dot, biv);
    }

    const f16x8* w1 = (const f16x8*)ldsW1;

    // ---- u_i, computed redundantly per wave (no barrier, no divergence cost)
    float cu[4], w2r[4];
    {
        f16x8 afu0 = cvt2(vi0, vi1);   // zeros for col!=0 -> A rows 1..15 zero
        f16x8 afu1 = cvt2(vi2, vi3);
#pragma unroll
        for (int nt = 0; nt < 4; nt++) {
            f32x4 ua = (f32x4){0.f, 0.f, 0.f, 0.f};
            ua = __builtin_amdgcn_mfma_f32_16x16x32_f16(afu0, w1[(0 * 4 + nt) * 64 + lane], ua, 0, 0, 0);
            ua = __builtin_amdgcn_mfma_f32_16x16x32_f16(afu1, w1[(1 * 4 + nt) * 64 + lane], ua, 0, 0, 0);
            // u_i[nt*16+col] lives in D row 0 = lane col (q==0), reg 0
            cu[nt] = ldsCC[nt * 16 + col] + __shfl(ua[0], col);
            w2r[nt] = ldsWs2[nt * 16 + col];
        }
    }

    // ---- phase 1: S = [h|v] @ [Wc; 0.25 Ws1], rolling v prefetch ----
#pragma unroll
    for (int jt4 = 0; jt4 < 4; jt4++) {
        int jt = wv * 4 + jt4;
        f16x8 av0 = cvt2(nf0, nf1);
        f16x8 av1 = cvt2(nf2, nf3);
        if (jt4 < 3) {
            const float* p = vB + ((jt + 1) * 16 + col) * 64 + q * 8;
            nf0 = *(const float4*)p;        nf1 = *(const float4*)(p + 4);
            nf2 = *(const float4*)(p + 32); nf3 = *(const float4*)(p + 36);
        }

        f32x4 acc[4];
#pragma unroll
        for (int nt = 0; nt < 4; nt++) {
            acc[nt] = (f32x4){0.f, 0.f, 0.f, 0.f};
            acc[nt] = __builtin_amdgcn_mfma_f32_16x16x32_f16(av0, w1[(0 * 4 + nt) * 64 + lane], acc[nt], 0, 0, 0);
            acc[nt] = __builtin_amdgcn_mfma_f32_16x16x32_f16(av1, w1[(1 * 4 + nt) * 64 + lane], acc[nt], 0, 0, 0);
        }

        float2 db = ldsDB[jt * 16 + col];
        _Float16 dh = (_Float16)db.x, bh = (_Float16)db.y;
        f16x8 d8, b8;
#pragma unroll
        for (int p = 0; p < 8; p++) { d8[p] = dh; b8[p] = bh; }
        f16x8 af0, af1;
        {
            f16x8 h0 = d8 * cfA[0] + b8 * cfB[0] + cfC[0];
            f16x8 h1 = d8 * cfA[1] + b8 * cfB[1] + cfC[1];
            af0 = __builtin_elementwise_max(h0, (f16x8)(_Float16)0.f);
            af1 = __builtin_elementwise_max(h1, (f16x8)(_Float16)0.f);
        }
#pragma unroll
        for (int nt = 0; nt < 4; nt++) {
            acc[nt] = __builtin_amdgcn_mfma_f32_16x16x32_f16(af0, wcf[0][nt], acc[nt], 0, 0, 0);
            acc[nt] = __builtin_amdgcn_mfma_f32_16x16x32_f16(af1, wcf[1][nt], acc[nt], 0, 0, 0);
        }

        float tr[4] = {0.f, 0.f, 0.f, 0.f};
#pragma unroll
        for (int nt = 0; nt < 4; nt++) {
#pragma unroll
            for (int r = 0; r < 4; r++) {
                float s = acc[nt][r] + cu[nt];
                tr[r] = fmaf(fmaxf(s, 0.f), w2r[nt], tr[r]);
            }
        }
#pragma unroll
        for (int m = 1; m < 16; m <<= 1) {
#pragma unroll
            for (int r = 0; r < 4; r++) tr[r] += __shfl_xor(tr[r], m);
        }
        if (col == 0)
            *(float4*)&ldsS[jt * 16 + q * 4] = make_float4(tr[0], tr[1], tr[2], tr[3]);
    }

    // ---- phase 2: row softmax + Sh (ldsS/ldsDB reads are wave-private) ----
    float sv = ldsS[t];
    float wm = sv;
#pragma unroll
    for (int md = 1; md < 64; md <<= 1) wm = fmaxf(wm, __shfl_xor(wm, md));
    if (lane == 0) ldsRedM[wv] = wm;
    __syncthreads();
    float m_row = fmaxf(fmaxf(ldsRedM[0], ldsRedM[1]), fmaxf(ldsRedM[2], ldsRedM[3]));
    float wgt = __expf(sv - m_row);
    float rsp = wgt;
#pragma unroll
    for (int md = 1; md < 64; md <<= 1) rsp += __shfl_xor(rsp, md);
    ldsS[t] = wgt;                      // own-slot overwrite
    if (lane == 0) ldsRedS[wv] = rsp;
    __syncthreads();
    float rowsum = ldsRedS[0] + ldsRedS[1] + ldsRedS[2] + ldsRedS[3];

    float A = Wv1[lane], B = Wv1[64 + lane], C = bv1[lane];
    float acc = 0.f;                    // lane = k; wave covers its 64 j's
#pragma unroll 8
    for (int jj = 0; jj < 64; jj++) {
        int j = wv * 64 + jj;
        float w = ldsS[j];              // broadcast, wave-local
        float2 db = ldsDB[j];
        float h = fmaxf(fmaf(db.x, A, fmaf(db.y, B, C)), 0.f);
        acc = fmaf(w, h, acc);
    }
    ldsP[wv][lane] = acc;
    __syncthreads();
    if (t < 64)
        ws[OFF_SHR + (b * 256 + i) * 64 + t] = ldsP[0][t] + ldsP[1][t] + ldsP[2][t] + ldsP[3][t];
    if (t == 0) {
        ws[OFF_MI  + b * 256 + i] = m_row;
        ws[OFF_RSI + b * 256 + i] = rowsum;
    }
}

// ---------------------------------------------------------------- final ----
__global__ __launch_bounds__(256) void k_final(
    const float* __restrict__ values, const float* __restrict__ Wv2,
    const float* __restrict__ bv2, const float* __restrict__ ws,
    float* __restrict__ out)
{
    __shared__ float scl[256], zl[256], red[4], pS[4][64], pA[4][64], shv[64], a2v[64];
    int b = blockIdx.x, t = threadIdx.x, wv = t >> 6, lane = t & 63;

    float mi = ws[OFF_MI + b * 256 + t];
    float wm = mi;
#pragma unroll
    for (int md = 1; md < 64; md <<= 1) wm = fmaxf(wm, __shfl_xor(wm, md));
    if (lane == 0) red[wv] = wm;
    __syncthreads();
    float M = fmaxf(fmaxf(red[0], red[1]), fmaxf(red[2], red[3]));

    float rs = ws[OFF_RSI + b * 256 + t];
    float sc = __expf(mi - M);
    float zt = sc * rs;
    scl[t] = sc; zl[t] = zt;
    float zp = zt;
#pragma unroll
    for (int md = 1; md < 64; md <<= 1) zp += __shfl_xor(zp, md);
    __syncthreads();
    if (lane == 0) red[wv] = zp;
    __syncthreads();
    float Z = red[0] + red[1] + red[2] + red[3];

    float accS = 0.f, accA = 0.f;
    const float* shrB = ws + OFF_SHR + b * 256 * 64;
    const float* vB   = values + b * 256 * 64;
#pragma unroll 4
    for (int jj = 0; jj < 64; jj++) {
        int row = wv * 64 + jj;
        accS = fmaf(scl[row], shrB[row * 64 + lane], accS);
        accA = fmaf(zl[row],  vB[row * 64 + lane],  accA);
    }
    pS[wv][lane] = accS; pA[wv][lane] = accA;
    __syncthreads();
    if (t < 64) {
        shv[t] = pS[0][t] + pS[1][t] + pS[2][t] + pS[3][t];
        a2v[t] = pA[0][t] + pA[1][t] + pA[2][t] + pA[3][t];
    }
    __syncthreads();
    if (t < 64) {
        float t1 = 0.f;
#pragma unroll 8
        for (int k = 0; k < 64; k++) t1 = fmaf(shv[k], Wv2[k * 64 + t], t1);
        out[b * 64 + t] = 0.5f * (t1 + a2v[t]) / Z + 0.5f * bv2[t];
    }
}

// ---------------------------------------------------------------- launch ---
extern "C" void kernel_launch(void* const* d_in, const int* in_sizes, int n_in,
                              void* d_out, int out_size, void* d_ws, size_t ws_size,
                              hipStream_t stream)
{
    const float* positions = (const float*)d_in[0];
    const float* values    = (const float*)d_in[1];
    const float* Wv1       = (const float*)d_in[2];
    const float* bv1       = (const float*)d_in[3];
    const float* Wv2       = (const float*)d_in[4];
    const float* bv2       = (const float*)d_in[5];
    const float* Ws1       = (const float*)d_in[6];
    const float* bs1       = (const float*)d_in[7];
    const float* Ws2       = (const float*)d_in[8];
    // d_in[9] = bs2: uniform shift on scores, cancels in softmax
    float* ws  = (float*)d_ws;
    float* out = (float*)d_out;

    k_setup<<<45, 256, 0, stream>>>(Wv1, bv1, Wv2, bv2, Ws1, bs1, ws);
    k_main<<<4096, 256, 0, stream>>>(positions, values, Wv1, bv1, Ws2, ws);  // 2x probe
    k_final<<<NB, 256, 0, stream>>>(values, Wv2, bv2, ws, out);
}

// Round 12
// 107.652 us; speedup vs baseline: 1.2035x; 1.2035x over previous
//
#include <hip/hip_runtime.h>
#include <hip/hip_bf16.h>
#include <hip/hip_fp16.h>

#define NB 8
#define NN 256
#define DD 64

// workspace layout (float offsets)
#define OFF_WCF   0        // 2048 f = 4096 f16 : Wc B-frags [ks][nt][lane][8]
#define OFF_CSF   2048     // 1536 f = 3072 f16 : h-coefs per lane [lane][coef][kslot16], stride 48
#define OFF_CC    3584     // 64   : cc[d] = 0.5*(bv2@Ws1)[d] + bs1[d]
#define OFF_MI    3648     // 2048 : per-row local max
#define OFF_RSI   5696     // 2048 : per-row rowsum (local frame)
#define OFF_SHR   7744     // 131072 : per-row Sh[64] (local frame)
#define OFF_P     138816   // 131072 : 0.25*V@Ws1, swizzled to C-frag order
                           //   [(b*16+jt)*4+nt][lane][r] : elem = tile*256 + lane*4 + r
                           //   holds P[j = jt*16 + (lane>>4)*4 + r][d = nt*16 + (lane&15)]
#define OFF_VF    269888   // 65536 f = 131072 f16 : values cast to f16, flat

typedef __attribute__((ext_vector_type(4))) float f32x4;
typedef _Float16 f16x8 __attribute__((ext_vector_type(8)));

// ---------------------------------------------------------------- setup ----
// items: P+VF 131072 | WCF 4096 | CSF 3072 | CC 64  => 138304 -> 541 blocks
__global__ __launch_bounds__(256) void k_setup(
    const float* __restrict__ values, const float* __restrict__ Wv1,
    const float* __restrict__ bv1, const float* __restrict__ Wv2,
    const float* __restrict__ bv2, const float* __restrict__ Ws1,
    const float* __restrict__ bs1, float* __restrict__ ws)
{
    int idx = blockIdx.x * 256 + threadIdx.x;
    if (idx < 131072) {
        // VF: flat f16 cast of values
        ((_Float16*)(ws + OFF_VF))[idx] = (_Float16)values[idx];
        // P (swizzled): decompose C-frag order index
        int r = idx & 3, lane = (idx >> 2) & 63, nt = (idx >> 8) & 3, jtg = idx >> 10;
        int b = jtg >> 4, jt = jtg & 15;
        int j = jt * 16 + (lane >> 4) * 4 + r;
        int d = nt * 16 + (lane & 15);
        const float* v = values + (b * 256 + j) * 64;
        float s = 0.f;
#pragma unroll 8
        for (int k = 0; k < 64; k++) s = fmaf(v[k], Ws1[k * 64 + d], s);
        ws[OFF_P + idx] = 0.25f * s;
    } else if (idx < 135168) {
        // Wc = 0.5*Wv2@Ws1 -> f16 B-fragment order
        int e = idx - 131072;
        int j = e & 7, ln = (e >> 3) & 63, nt = (e >> 9) & 3, ks = e >> 11;
        int k = ks * 32 + (ln >> 4) * 8 + j;
        int d = nt * 16 + (ln & 15);
        float s = 0.f;
#pragma unroll 8
        for (int m = 0; m < 64; m++) s = fmaf(Wv2[k * 64 + m], Ws1[m * 64 + d], s);
        ((_Float16*)(ws + OFF_WCF))[e] = (_Float16)(0.5f * s);
    } else if (idx < 138240) {
        // h-coefs: stride-48 per lane: [lane][coef(3)][kslot(16)]
        int e = idx - 135168;          // 0..3071
        int ln = e / 48;
        int rem = e - ln * 48;
        int coef = rem >> 4, kslot = rem & 15;
        int ks = kslot >> 3, j = kslot & 7;
        int k = ks * 32 + (ln >> 4) * 8 + j;
        float v = (coef == 0) ? Wv1[k] : (coef == 1) ? Wv1[64 + k] : bv1[k];
        ((_Float16*)(ws + OFF_CSF))[ln * 48 + coef * 16 + kslot] = (_Float16)v;
    } else if (idx < 138304) {
        int d = idx - 138240;
        float s = 0.f;
#pragma unroll 8
        for (int k = 0; k < 64; k++) s = fmaf(bv2[k], Ws1[k * 64 + d], s);
        ws[OFF_CC + d] = 0.5f * s + bs1[d];
    }
}

// ----------------------------------------------------------------- main ----
// 2048 blocks = 8 batches * 256 rows; 256 threads (4 waves), one row i each.
// All row-invariant GEMM work (u = 0.25 V@Ws1, f16 cast of V) is precomputed;
// per jt4: 6 coalesced vector loads + 8 MFMA + epilogue.
__global__ __launch_bounds__(256, 4) void k_main(
    const float* __restrict__ pos, const float* __restrict__ Wv1,
    const float* __restrict__ bv1, const float* __restrict__ Ws2,
    float* __restrict__ ws)
{
    __shared__ float2 ldsDB[256];    // (dot,biv) per j  (wave-private use)
    __shared__ float  ldsS[256];     // scores, then weights (wave-private use)
    __shared__ float  ldsCC[64];
    __shared__ float  ldsWs2[64];
    __shared__ float  ldsPos[3];
    __shared__ float  ldsRedM[4];
    __shared__ float  ldsRedS[4];
    __shared__ float  ldsP[4][64];

    int b = blockIdx.x >> 8;
    int i = blockIdx.x & 255;
    int t = threadIdx.x;
    int lane = t & 63, wv = t >> 6;
    int q = lane >> 4, col = lane & 15;

    // ---- per-lane constants from ws (global, block-invariant) ----
    f16x8 cfA[2], cfB[2], cfC[2];
    {
        const f16x8* cs = (const f16x8*)((const _Float16*)(ws + OFF_CSF) + lane * 48);
        cfA[0] = cs[0]; cfA[1] = cs[1];
        cfB[0] = cs[2]; cfB[1] = cs[3];
        cfC[0] = cs[4]; cfC[1] = cs[5];
    }
    f16x8 wcf[2][4];
    {
        const f16x8* p = (const f16x8*)(ws + OFF_WCF);
#pragma unroll
        for (int ks = 0; ks < 2; ks++)
#pragma unroll
            for (int nt = 0; nt < 4; nt++)
                wcf[ks][nt] = p[(ks * 4 + nt) * 64 + lane];
    }
    if (t < 3)  ldsPos[t] = pos[(b * 256 + i) * 3 + t];
    if (t >= 64 && t < 128) ldsCC[t - 64] = ws[OFF_CC + t - 64];
    if (t >= 128 && t < 192) ldsWs2[t - 128] = Ws2[t - 128];
    __syncthreads();

    {   // dot/biv vs all j (thread t = j); consumed wave-locally (no barrier)
        float px = pos[(b * 256 + t) * 3 + 0];
        float py = pos[(b * 256 + t) * 3 + 1];
        float pz = pos[(b * 256 + t) * 3 + 2];
        float ax = ldsPos[0], ay = ldsPos[1], az = ldsPos[2];
        float dot = ax * px + ay * py + az * pz;
        float cx = ay * pz - az * py;
        float cy = az * px - ax * pz;
        float cz = ax * py - ay * px;
        float biv = sqrtf(cx * cx + cy * cy + cz * cz + 1e-20f);
        ldsDB[t] = make_float2(dot, biv);
    }

    const float* Pb = ws + OFF_P + b * 16384;         // swizzled P for batch b
    const _Float16* vfB = (const _Float16*)(ws + OFF_VF) + b * (NN * DD);

    // ---- cu[nt] = cc[d] + u_i[d], d = nt*16+col (u_i from swizzled P) ----
    float cu[4], w2r[4];
    {
        int jti = i >> 4, qq = (i >> 2) & 3, rr = i & 3;
#pragma unroll
        for (int nt = 0; nt < 4; nt++) {
            cu[nt] = ldsCC[nt * 16 + col] + Pb[(jti * 4 + nt) * 256 + qq * 64 + col * 4 + rr];
            w2r[nt] = ldsWs2[nt * 16 + col];
        }
    }

    // ---- phase 1: S = h @ Wc + (precomputed u_j) + cu, relu, .Ws2 ----
#pragma unroll
    for (int jt4 = 0; jt4 < 4; jt4++) {
        int jt = wv * 4 + jt4;
        // v A-frags (f16, precast)
        const _Float16* vrow = vfB + (jt * 16 + col) * 64;
        f16x8 av0 = *(const f16x8*)(vrow + q * 8);
        f16x8 av1 = *(const f16x8*)(vrow + 32 + q * 8);
        // accumulator init = u_j tile in C-frag order (coalesced f32x4)
        f32x4 acc[4];
        const float* Pt = Pb + (jt * 4) * 256 + lane * 4;
#pragma unroll
        for (int nt = 0; nt < 4; nt++)
            acc[nt] = *(const f32x4*)(Pt + nt * 256);

        float2 db = ldsDB[jt * 16 + col];
        _Float16 dh = (_Float16)db.x, bh = (_Float16)db.y;
        f16x8 d8, b8;
#pragma unroll
        for (int p = 0; p < 8; p++) { d8[p] = dh; b8[p] = bh; }
        f16x8 af0, af1;
        {
            f16x8 h0 = d8 * cfA[0] + b8 * cfB[0] + cfC[0];
            f16x8 h1 = d8 * cfA[1] + b8 * cfB[1] + cfC[1];
            af0 = __builtin_elementwise_max(h0, (f16x8)(_Float16)0.f);
            af1 = __builtin_elementwise_max(h1, (f16x8)(_Float16)0.f);
        }
#pragma unroll
        for (int nt = 0; nt < 4; nt++) {
            acc[nt] = __builtin_amdgcn_mfma_f32_16x16x32_f16(av0, wcf[0][nt], acc[nt], 0, 0, 0);
            acc[nt] = __builtin_amdgcn_mfma_f32_16x16x32_f16(av1, wcf[1][nt], acc[nt], 0, 0, 0);
        }
        // NOTE: wcf here is Wc only; u_j came in through acc init.
        // (h uses af0/af1 with the SAME wcf — correct because the GEMM is
        //  h@Wc; the v@0.25Ws1 part is the precomputed acc init.)
        // -- oops guard: the two MFMAs above must use af, not av. Corrected:
        // (see actual code below)

        float tr[4] = {0.f, 0.f, 0.f, 0.f};
#pragma unroll
        for (int nt = 0; nt < 4; nt++) {
            // fix-up: redo with af (av-based lines above are replaced here)
            f32x4 a2 = *(const f32x4*)(Pt + nt * 256);
            a2 = __builtin_amdgcn_mfma_f32_16x16x32_f16(af0, wcf[0][nt], a2, 0, 0, 0);
            a2 = __builtin_amdgcn_mfma_f32_16x16x32_f16(af1, wcf[1][nt], a2, 0, 0, 0);
#pragma unroll
            for (int r = 0; r < 4; r++) {
                float s = a2[r] + cu[nt];
                tr[r] = fmaf(fmaxf(s, 0.f), w2r[nt], tr[r]);
            }
        }
        (void)av0; (void)av1; (void)acc;
#pragma unroll
        for (int m = 1; m < 16; m <<= 1) {
#pragma unroll
            for (int r = 0; r < 4; r++) tr[r] += __shfl_xor(tr[r], m);
        }
        if (col == 0)
            *(float4*)&ldsS[jt * 16 + q * 4] = make_float4(tr[0], tr[1], tr[2], tr[3]);
    }

    // ---- phase 2: row softmax + Sh (ldsS/ldsDB reads wave-private) ----
    float sv = ldsS[t];
    float wm = sv;
#pragma unroll
    for (int md = 1; md < 64; md <<= 1) wm = fmaxf(wm, __shfl_xor(wm, md));
    if (lane == 0) ldsRedM[wv] = wm;
    __syncthreads();
    float m_row = fmaxf(fmaxf(ldsRedM[0], ldsRedM[1]), fmaxf(ldsRedM[2], ldsRedM[3]));
    float wgt = __expf(sv - m_row);
    float rsp = wgt;
#pragma unroll
    for (int md = 1; md < 64; md <<= 1) rsp += __shfl_xor(rsp, md);
    ldsS[t] = wgt;                      // own-slot overwrite
    if (lane == 0) ldsRedS[wv] = rsp;
    __syncthreads();
    float rowsum = ldsRedS[0] + ldsRedS[1] + ldsRedS[2] + ldsRedS[3];

    float A = Wv1[lane], B = Wv1[64 + lane], C = bv1[lane];
    float acc2 = 0.f;                   // lane = k; wave covers its 64 j's
#pragma unroll 8
    for (int jj = 0; jj < 64; jj++) {
        int j = wv * 64 + jj;
        float w = ldsS[j];
        float2 db = ldsDB[j];
        float h = fmaxf(fmaf(db.x, A, fmaf(db.y, B, C)), 0.f);
        acc2 = fmaf(w, h, acc2);
    }
    ldsP[wv][lane] = acc2;
    __syncthreads();
    if (t < 64)
        ws[OFF_SHR + (b * 256 + i) * 64 + t] = ldsP[0][t] + ldsP[1][t] + ldsP[2][t] + ldsP[3][t];
    if (t == 0) {
        ws[OFF_MI  + b * 256 + i] = m_row;
        ws[OFF_RSI + b * 256 + i] = rowsum;
    }
}

// ---------------------------------------------------------------- final ----
__global__ __launch_bounds__(256) void k_final(
    const float* __restrict__ values, const float* __restrict__ Wv2,
    const float* __restrict__ bv2, const float* __restrict__ ws,
    float* __restrict__ out)
{
    __shared__ float scl[256], zl[256], red[4], pS[4][64], pA[4][64], shv[64], a2v[64];
    int b = blockIdx.x, t = threadIdx.x, wv = t >> 6, lane = t & 63;

    float mi = ws[OFF_MI + b * 256 + t];
    float wm = mi;
#pragma unroll
    for (int md = 1; md < 64; md <<= 1) wm = fmaxf(wm, __shfl_xor(wm, md));
    if (lane == 0) red[wv] = wm;
    __syncthreads();
    float M = fmaxf(fmaxf(red[0], red[1]), fmaxf(red[2], red[3]));

    float rs = ws[OFF_RSI + b * 256 + t];
    float sc = __expf(mi - M);
    float zt = sc * rs;
    scl[t] = sc; zl[t] = zt;
    float zp = zt;
#pragma unroll
    for (int md = 1; md < 64; md <<= 1) zp += __shfl_xor(zp, md);
    __syncthreads();
    if (lane == 0) red[wv] = zp;
    __syncthreads();
    float Z = red[0] + red[1] + red[2] + red[3];

    float accS = 0.f, accA = 0.f;
    const float* shrB = ws + OFF_SHR + b * 256 * 64;
    const float* vB   = values + b * 256 * 64;
#pragma unroll 4
    for (int jj = 0; jj < 64; jj++) {
        int row = wv * 64 + jj;
        accS = fmaf(scl[row], shrB[row * 64 + lane], accS);
        accA = fmaf(zl[row],  vB[row * 64 + lane],  accA);
    }
    pS[wv][lane] = accS; pA[wv][lane] = accA;
    __syncthreads();
    if (t < 64) {
        shv[t] = pS[0][t] + pS[1][t] + pS[2][t] + pS[3][t];
        a2v[t] = pA[0][t] + pA[1][t] + pA[2][t] + pA[3][t];
    }
    __syncthreads();
    if (t < 64) {
        float t1 = 0.f;
#pragma unroll 8
        for (int k = 0; k < 64; k++) t1 = fmaf(shv[k], Wv2[k * 64 + t], t1);
        out[b * 64 + t] = 0.5f * (t1 + a2v[t]) / Z + 0.5f * bv2[t];
    }
}

// ---------------------------------------------------------------- launch ---
extern "C" void kernel_launch(void* const* d_in, const int* in_sizes, int n_in,
                              void* d_out, int out_size, void* d_ws, size_t ws_size,
                              hipStream_t stream)
{
    const float* positions = (const float*)d_in[0];
    const float* values    = (const float*)d_in[1];
    const float* Wv1       = (const float*)d_in[2];
    const float* bv1       = (const float*)d_in[3];
    const float* Wv2       = (const float*)d_in[4];
    const float* bv2       = (const float*)d_in[5];
    const float* Ws1       = (const float*)d_in[6];
    const float* bs1       = (const float*)d_in[7];
    const float* Ws2       = (const float*)d_in[8];
    // d_in[9] = bs2: uniform shift on scores, cancels in softmax
    float* ws  = (float*)d_ws;
    float* out = (float*)d_out;

    k_setup<<<541, 256, 0, stream>>>(values, Wv1, bv1, Wv2, bv2, Ws1, bs1, ws);
    k_main<<<2048, 256, 0, stream>>>(positions, Wv1, bv1, Ws2, ws);
    k_final<<<NB, 256, 0, stream>>>(values, Wv2, bv2, ws, out);
}

// Round 13
// 99.692 us; speedup vs baseline: 1.2996x; 1.0798x over previous
//
#include <hip/hip_runtime.h>
#include <hip/hip_bf16.h>
#include <hip/hip_fp16.h>

#define NB 8
#define NN 256
#define DD 64

// workspace layout (float offsets)
#define OFF_WCF   0        // 2048 f = 4096 f16 : Wc B-frags [ks][nt][lane][8]
#define OFF_CSF   2048     // 1536 f = 3072 f16 : h-coefs per lane [lane][coef][kslot16], stride 48
#define OFF_CC    3584     // 64   : cc[d] = 0.5*(bv2@Ws1)[d] + bs1[d]
#define OFF_MI    3648     // 2048 : per-row local max
#define OFF_RSI   5696     // 2048 : per-row rowsum (local frame)
#define OFF_SHR   7744     // 131072 : per-row Sh[64] (local frame)
#define OFF_P     138816   // 131072 : 0.25*V@Ws1, swizzled to C-frag order
                           //   elem idx = jtg*1024 + nt*256 + lane*4 + r
                           //   holds P[j = jt*16 + (lane>>4)*4 + r][d = nt*16 + (lane&15)]

typedef __attribute__((ext_vector_type(4))) float f32x4;
typedef _Float16 f16x8 __attribute__((ext_vector_type(8)));

// ---------------------------------------------------------------- setup ----
// items: P 131072 | WCF 4096 | CSF 3072 | CC 64  => 138304 -> 541 blocks
__global__ __launch_bounds__(256) void k_setup(
    const float* __restrict__ values, const float* __restrict__ Wv1,
    const float* __restrict__ bv1, const float* __restrict__ Wv2,
    const float* __restrict__ bv2, const float* __restrict__ Ws1,
    const float* __restrict__ bs1, float* __restrict__ ws)
{
    int idx = blockIdx.x * 256 + threadIdx.x;
    if (idx < 131072) {
        // P (swizzled to C-frag order): 0.25 * (v[b,j,:] @ Ws1)[d]
        int r = idx & 3, lane = (idx >> 2) & 63, nt = (idx >> 8) & 3, jtg = idx >> 10;
        int b = jtg >> 4, jt = jtg & 15;
        int j = jt * 16 + (lane >> 4) * 4 + r;
        int d = nt * 16 + (lane & 15);
        const float* v = values + (b * 256 + j) * 64;
        float s = 0.f;
#pragma unroll 8
        for (int k = 0; k < 64; k++) s = fmaf(v[k], Ws1[k * 64 + d], s);
        ws[OFF_P + idx] = 0.25f * s;
    } else if (idx < 135168) {
        // Wc = 0.5*Wv2@Ws1 -> f16 B-fragment order
        int e = idx - 131072;
        int j = e & 7, ln = (e >> 3) & 63, nt = (e >> 9) & 3, ks = e >> 11;
        int k = ks * 32 + (ln >> 4) * 8 + j;
        int d = nt * 16 + (ln & 15);
        float s = 0.f;
#pragma unroll 8
        for (int m = 0; m < 64; m++) s = fmaf(Wv2[k * 64 + m], Ws1[m * 64 + d], s);
        ((_Float16*)(ws + OFF_WCF))[e] = (_Float16)(0.5f * s);
    } else if (idx < 138240) {
        // h-coefs: stride-48 per lane: [lane][coef(3)][kslot(16)]
        int e = idx - 135168;          // 0..3071
        int ln = e / 48;
        int rem = e - ln * 48;
        int coef = rem >> 4, kslot = rem & 15;
        int ks = kslot >> 3, j = kslot & 7;
        int k = ks * 32 + (ln >> 4) * 8 + j;
        float v = (coef == 0) ? Wv1[k] : (coef == 1) ? Wv1[64 + k] : bv1[k];
        ((_Float16*)(ws + OFF_CSF))[ln * 48 + coef * 16 + kslot] = (_Float16)v;
    } else if (idx < 138304) {
        int d = idx - 138240;
        float s = 0.f;
#pragma unroll 8
        for (int k = 0; k < 64; k++) s = fmaf(bv2[k], Ws1[k * 64 + d], s);
        ws[OFF_CC + d] = 0.5f * s + bs1[d];
    }
}

// ----------------------------------------------------------------- main ----
// 1024 blocks = 8 batches * 128 i-pairs (2 rows/block amortizes fixed cost);
// 256 threads (4 waves). Per jt4: P-tile C-init (shared by both rows) +
// 8 MFMA per row (h@Wc only). u_j/u_i fully precomputed in P.
__global__ __launch_bounds__(256, 4) void k_main(
    const float* __restrict__ pos, const float* __restrict__ Wv1,
    const float* __restrict__ bv1, const float* __restrict__ Ws2,
    float* __restrict__ ws)
{
    __shared__ float4 ldsDB[256];    // per j: {dot0,biv0,dot1,biv1} (wave-private use)
    __shared__ float2 ldsS[256];     // per j: {s0,s1} scores, then weights
    __shared__ float  ldsCC[64];
    __shared__ float  ldsWs2[64];
    __shared__ float  ldsPos[6];
    __shared__ float  ldsRedM[2][4];
    __shared__ float  ldsRedS[2][4];
    __shared__ float  ldsP[2][4][64];

    int b  = blockIdx.x >> 7;
    int i0 = (blockIdx.x & 127) * 2;
    int t  = threadIdx.x;
    int lane = t & 63, wv = t >> 6;
    int q = lane >> 4, col = lane & 15;

    // ---- per-lane constants from ws (block-invariant) ----
    f16x8 cfA[2], cfB[2], cfC[2];
    {
        const f16x8* cs = (const f16x8*)((const _Float16*)(ws + OFF_CSF) + lane * 48);
        cfA[0] = cs[0]; cfA[1] = cs[1];
        cfB[0] = cs[2]; cfB[1] = cs[3];
        cfC[0] = cs[4]; cfC[1] = cs[5];
    }
    f16x8 wcf[2][4];
    {
        const f16x8* p = (const f16x8*)(ws + OFF_WCF);
#pragma unroll
        for (int ks = 0; ks < 2; ks++)
#pragma unroll
            for (int nt = 0; nt < 4; nt++)
                wcf[ks][nt] = p[(ks * 4 + nt) * 64 + lane];
    }
    if (t < 6)  ldsPos[t] = pos[(b * 256 + i0) * 3 + t];
    if (t >= 64 && t < 128) ldsCC[t - 64] = ws[OFF_CC + t - 64];
    if (t >= 128 && t < 192) ldsWs2[t - 128] = Ws2[t - 128];
    __syncthreads();

    {   // dot/biv for both rows vs all j (thread t = j); consumed wave-locally
        float px = pos[(b * 256 + t) * 3 + 0];
        float py = pos[(b * 256 + t) * 3 + 1];
        float pz = pos[(b * 256 + t) * 3 + 2];
        float4 r;
        {
            float ax = ldsPos[0], ay = ldsPos[1], az = ldsPos[2];
            r.x = ax * px + ay * py + az * pz;
            float cx = ay * pz - az * py, cy = az * px - ax * pz, cz = ax * py - ay * px;
            r.y = sqrtf(cx * cx + cy * cy + cz * cz + 1e-20f);
        }
        {
            float ax = ldsPos[3], ay = ldsPos[4], az = ldsPos[5];
            r.z = ax * px + ay * py + az * pz;
            float cx = ay * pz - az * py, cy = az * px - ax * pz, cz = ax * py - ay * px;
            r.w = sqrtf(cx * cx + cy * cy + cz * cz + 1e-20f);
        }
        ldsDB[t] = r;
    }

    const float* Pb = ws + OFF_P + b * 16384;   // swizzled P for batch b

    // ---- cu[ii][nt] = cc[d] + u_i[d] (u_i from swizzled P lookup) ----
    float cu[2][4], w2r[4];
#pragma unroll
    for (int ii = 0; ii < 2; ii++) {
        int i = i0 + ii;
        int jti = i >> 4, qq = (i >> 2) & 3, rr = i & 3;
#pragma unroll
        for (int nt = 0; nt < 4; nt++)
            cu[ii][nt] = ldsCC[nt * 16 + col] + Pb[(jti * 4 + nt) * 256 + qq * 64 + col * 4 + rr];
    }
#pragma unroll
    for (int nt = 0; nt < 4; nt++) w2r[nt] = ldsWs2[nt * 16 + col];

    // ---- phase 1: S = h @ Wc + P(u_j) + cu, relu, .Ws2, reduce over d ----
#pragma unroll
    for (int jt4 = 0; jt4 < 4; jt4++) {
        int jt = wv * 4 + jt4;
        // u_j tile in C-frag order (coalesced f32x4), shared by both rows
        f32x4 ptile[4];
        const float* Pt = Pb + (jt * 4) * 256 + lane * 4;
#pragma unroll
        for (int nt = 0; nt < 4; nt++)
            ptile[nt] = *(const f32x4*)(Pt + nt * 256);

        float4 db4 = ldsDB[jt * 16 + col];
#pragma unroll
        for (int ii = 0; ii < 2; ii++) {
            _Float16 dh = (_Float16)(ii ? db4.z : db4.x);
            _Float16 bh = (_Float16)(ii ? db4.w : db4.y);
            f16x8 d8, b8;
#pragma unroll
            for (int p = 0; p < 8; p++) { d8[p] = dh; b8[p] = bh; }
            f16x8 af0, af1;
            {
                f16x8 h0 = d8 * cfA[0] + b8 * cfB[0] + cfC[0];
                f16x8 h1 = d8 * cfA[1] + b8 * cfB[1] + cfC[1];
                af0 = __builtin_elementwise_max(h0, (f16x8)(_Float16)0.f);
                af1 = __builtin_elementwise_max(h1, (f16x8)(_Float16)0.f);
            }
            float tr[4] = {0.f, 0.f, 0.f, 0.f};
#pragma unroll
            for (int nt = 0; nt < 4; nt++) {
                f32x4 a2 = __builtin_amdgcn_mfma_f32_16x16x32_f16(af0, wcf[0][nt], ptile[nt], 0, 0, 0);
                a2 = __builtin_amdgcn_mfma_f32_16x16x32_f16(af1, wcf[1][nt], a2, 0, 0, 0);
#pragma unroll
                for (int r = 0; r < 4; r++) {
                    float s = a2[r] + cu[ii][nt];
                    tr[r] = fmaf(fmaxf(s, 0.f), w2r[nt], tr[r]);
                }
            }
#pragma unroll
            for (int m = 1; m < 16; m <<= 1) {
#pragma unroll
                for (int r = 0; r < 4; r++) tr[r] += __shfl_xor(tr[r], m);
            }
            if (col == 0) {
#pragma unroll
                for (int r = 0; r < 4; r++)
                    ldsS[jt * 16 + q * 4 + r][ii] = tr[r];
            }
        }
    }

    // ---- phase 2: row softmax + Sh, both rows fused (wave-private LDS) ----
    float2 sv = ldsS[t];
    float wm0 = sv.x, wm1 = sv.y;
#pragma unroll
    for (int md = 1; md < 64; md <<= 1) {
        wm0 = fmaxf(wm0, __shfl_xor(wm0, md));
        wm1 = fmaxf(wm1, __shfl_xor(wm1, md));
    }
    if (lane == 0) { ldsRedM[0][wv] = wm0; ldsRedM[1][wv] = wm1; }
    __syncthreads();
    float m0 = fmaxf(fmaxf(ldsRedM[0][0], ldsRedM[0][1]), fmaxf(ldsRedM[0][2], ldsRedM[0][3]));
    float m1 = fmaxf(fmaxf(ldsRedM[1][0], ldsRedM[1][1]), fmaxf(ldsRedM[1][2], ldsRedM[1][3]));
    float w0 = __expf(sv.x - m0), w1 = __expf(sv.y - m1);
    float rs0 = w0, rs1 = w1;
#pragma unroll
    for (int md = 1; md < 64; md <<= 1) {
        rs0 += __shfl_xor(rs0, md);
        rs1 += __shfl_xor(rs1, md);
    }
    ldsS[t] = make_float2(w0, w1);        // own-slot overwrite
    if (lane == 0) { ldsRedS[0][wv] = rs0; ldsRedS[1][wv] = rs1; }
    __syncthreads();
    float rowsum0 = ldsRedS[0][0] + ldsRedS[0][1] + ldsRedS[0][2] + ldsRedS[0][3];
    float rowsum1 = ldsRedS[1][0] + ldsRedS[1][1] + ldsRedS[1][2] + ldsRedS[1][3];

    float A = Wv1[lane], B = Wv1[64 + lane], C = bv1[lane];
    float acc0 = 0.f, acc1 = 0.f;         // lane = k; wave covers its 64 j's
#pragma unroll 8
    for (int jj = 0; jj < 64; jj++) {
        int j = wv * 64 + jj;
        float2 wj = ldsS[j];              // broadcast, wave-local
        float4 db = ldsDB[j];
        float h0 = fmaxf(fmaf(db.x, A, fmaf(db.y, B, C)), 0.f);
        float h1 = fmaxf(fmaf(db.z, A, fmaf(db.w, B, C)), 0.f);
        acc0 = fmaf(wj.x, h0, acc0);
        acc1 = fmaf(wj.y, h1, acc1);
    }
    ldsP[0][wv][lane] = acc0;
    ldsP[1][wv][lane] = acc1;
    __syncthreads();
    if (t < 128) {
        int ii = t >> 6, k = t & 63;
        ws[OFF_SHR + (b * 256 + i0 + ii) * 64 + k] =
            ldsP[ii][0][k] + ldsP[ii][1][k] + ldsP[ii][2][k] + ldsP[ii][3][k];
    }
    if (t == 0) {
        ws[OFF_MI  + b * 256 + i0]     = m0;
        ws[OFF_MI  + b * 256 + i0 + 1] = m1;
        ws[OFF_RSI + b * 256 + i0]     = rowsum0;
        ws[OFF_RSI + b * 256 + i0 + 1] = rowsum1;
    }
}

// ---------------------------------------------------------------- final ----
// 8 blocks x 1024 threads (16 waves): 4x less serial depth than 256-thread.
__global__ __launch_bounds__(1024) void k_final(
    const float* __restrict__ values, const float* __restrict__ Wv2,
    const float* __restrict__ bv2, const float* __restrict__ ws,
    float* __restrict__ out)
{
    __shared__ float scl[256], zl[256], redM[4], redZ[4];
    __shared__ float pS[16][64], pA[16][64], shv[64], a2v[64];
    int b = blockIdx.x, t = threadIdx.x, wv = t >> 6, lane = t & 63;

    float mi = 0.f;
    if (t < 256) {
        mi = ws[OFF_MI + b * 256 + t];
        float wm = mi;
#pragma unroll
        for (int md = 1; md < 64; md <<= 1) wm = fmaxf(wm, __shfl_xor(wm, md));
        if (lane == 0) redM[wv] = wm;
    }
    __syncthreads();
    if (t < 256) {
        float M = fmaxf(fmaxf(redM[0], redM[1]), fmaxf(redM[2], redM[3]));
        float rs = ws[OFF_RSI + b * 256 + t];
        float sc = __expf(mi - M);
        float zt = sc * rs;
        scl[t] = sc; zl[t] = zt;
        float zp = zt;
#pragma unroll
        for (int md = 1; md < 64; md <<= 1) zp += __shfl_xor(zp, md);
        if (lane == 0) redZ[wv] = zp;
    }
    __syncthreads();
    float Z = redZ[0] + redZ[1] + redZ[2] + redZ[3];

    // wave wv accumulates rows [wv*16, wv*16+16)
    float accS = 0.f, accA = 0.f;
    const float* shrB = ws + OFF_SHR + b * 256 * 64;
    const float* vB   = values + b * 256 * 64;
#pragma unroll
    for (int jj = 0; jj < 16; jj++) {
        int row = wv * 16 + jj;
        accS = fmaf(scl[row], shrB[row * 64 + lane], accS);
        accA = fmaf(zl[row],  vB[row * 64 + lane],  accA);
    }
    pS[wv][lane] = accS; pA[wv][lane] = accA;
    __syncthreads();
    if (t < 64) {
        float s1 = 0.f, s2 = 0.f;
#pragma unroll
        for (int w = 0; w < 16; w++) { s1 += pS[w][t]; s2 += pA[w][t]; }
        shv[t] = s1; a2v[t] = s2;
    }
    __syncthreads();
    if (t < 64) {
        float t1 = 0.f;
#pragma unroll 8
        for (int k = 0; k < 64; k++) t1 = fmaf(shv[k], Wv2[k * 64 + t], t1);
        out[b * 64 + t] = 0.5f * (t1 + a2v[t]) / Z + 0.5f * bv2[t];
    }
}

// ---------------------------------------------------------------- launch ---
extern "C" void kernel_launch(void* const* d_in, const int* in_sizes, int n_in,
                              void* d_out, int out_size, void* d_ws, size_t ws_size,
                              hipStream_t stream)
{
    const float* positions = (const float*)d_in[0];
    const float* values    = (const float*)d_in[1];
    const float* Wv1       = (const float*)d_in[2];
    const float* bv1       = (const float*)d_in[3];
    const float* Wv2       = (const float*)d_in[4];
    const float* bv2       = (const float*)d_in[5];
    const float* Ws1       = (const float*)d_in[6];
    const float* bs1       = (const float*)d_in[7];
    const float* Ws2       = (const float*)d_in[8];
    // d_in[9] = bs2: uniform shift on scores, cancels in softmax
    float* ws  = (float*)d_ws;
    float* out = (float*)d_out;

    k_setup<<<541, 256, 0, stream>>>(values, Wv1, bv1, Wv2, bv2, Ws1, bs1, ws);
    k_main<<<1024, 256, 0, stream>>>(positions, Wv1, bv1, Ws2, ws);
    k_final<<<NB, 1024, 0, stream>>>(values, Wv2, bv2, ws, out);
}